// Round 2
// baseline (1122.672 us; speedup 1.0000x reference)
//
#include <hip/hip_runtime.h>
#include <hip/hip_bf16.h>

// DimeNet InteractionBlock, MI355X/gfx950.
// Float tensors are FLOAT32 at the memory interface (per reference dtypes);
// internal GEMMs use bf16 MFMA (threshold 0.10875 permits bf16 compute).
// Stage A (kA): e_down = silu( (silu(x Wkj+b) * silu(rbf Wrbf2+b)) Wdown + b )  [E,128] bf16 -> ws
// Stage B (kB): t = silu( (e_down[idx_kj] * silu(silu(sbf W1) W2)) Wup + b );
//               f32 atomicAdd into mb[idx_ji]                                   [E,128] f32 -> ws
// Stage C (kC): out = mb + silu(silu(mb Wr1a+b) Wr1b+b) + x                     [E,128] f32
//
// MFMA 16x16x32 bf16; per-wave 16-row tiles; weights pre-packed (f32->bf16) in
// LDS in fragment order (conflict-free ds_read_b128); C->A layout transitions
// via per-wave LDS round-trip tile (same-wave DS ops are in-order).

#define HD 128

typedef short  short8 __attribute__((ext_vector_type(8)));
typedef __bf16 bf16x8 __attribute__((ext_vector_type(8)));
typedef float  f32x4  __attribute__((ext_vector_type(4)));

__device__ __forceinline__ float b2f(short s) {
    unsigned u = ((unsigned)(unsigned short)s) << 16;
    return __builtin_bit_cast(float, u);
}
__device__ __forceinline__ short f2b(float f) {
    return __builtin_bit_cast(short, __float2bfloat16(f));
}
__device__ __forceinline__ float silu_f(float v) {
    return v * __builtin_amdgcn_rcpf(1.0f + __expf(-v));
}
__device__ __forceinline__ short8 ld8(const short* p) { return *(const short8*)p; }

__device__ __forceinline__ f32x4 mfma16(short8 a, short8 b, f32x4 c) {
    return __builtin_amdgcn_mfma_f32_16x16x32_bf16(
        __builtin_bit_cast(bf16x8, a), __builtin_bit_cast(bf16x8, b), c, 0, 0, 0);
}

// Convert 8 consecutive f32 at p to a bf16 short8 A-fragment chunk.
__device__ __forceinline__ short8 ld8f(const float* p) {
    f32x4 v0 = *(const f32x4*)p;
    f32x4 v1 = *(const f32x4*)(p + 4);
    short8 r;
#pragma unroll
    for (int j = 0; j < 4; j++) { r[j] = f2b(v0[j]); r[4 + j] = f2b(v1[j]); }
    return r;
}

// Pack f32 weight W[K x 128] (row-major) into LDS bf16 fragment order:
// frag[((ct*KC+kc)*64 + lane)*8 + j] = B[k=kc*32+(lane>>4)*8+j][n=ct*16+(lane&15)]
// k >= Kact zero-filled.
__device__ void pack_weight(const float* __restrict__ W, int Kact, int KC,
                            short* frag, int tid, int nth) {
    int total = 8 * KC * 64;
    for (int e = tid; e < total; e += nth) {
        int lane = e & 63;
        int slot = e >> 6;          // ct*KC + kc
        int ct = slot / KC;
        int kc = slot - ct * KC;
        int n  = ct * 16 + (lane & 15);
        int kb = kc * 32 + (lane >> 4) * 8;
        short8 v;
#pragma unroll
        for (int j = 0; j < 8; j++) {
            int k = kb + j;
            v[j] = (k < Kact) ? f2b(W[k * HD + n]) : (short)0;
        }
        *(short8*)&frag[(slot * 64 + lane) * 8] = v;
    }
}

template <int KC>
__device__ __forceinline__ void gemm8(const short8* a, const short* fragW,
                                      int lane, f32x4* acc) {
#pragma unroll
    for (int kc = 0; kc < KC; kc++) {
#pragma unroll
        for (int ct = 0; ct < 8; ct++) {
            short8 b = ld8(&fragW[((ct * KC + kc) * 64 + lane) * 8]);
            acc[ct] = mfma16(a[kc], b, acc[ct]);
        }
    }
}

#define RT_S 136  // round-trip tile stride (bf16 elems); 272B rows, 16B-aligned

// ---------------- Stage A ----------------
extern "C" __global__ __launch_bounds__(512)
void kA(const float* __restrict__ x, const float* __restrict__ rbf,
        const float* __restrict__ Wkj, const float* __restrict__ bkj,
        const float* __restrict__ Wrbf2, const float* __restrict__ brbf2,
        const float* __restrict__ Wdown, const float* __restrict__ bdown,
        short* __restrict__ e_down, int ntiles) {
    extern __shared__ short smem[];
    short* fW1 = smem;               // 8*4*64*8 = 16384 shorts = 32 KB
    short* fW2 = fW1 + 16384;
    short* fW3 = fW2 + 16384;
    short* rt0 = fW3 + 16384;        // 8 waves * 16*RT_S
    int tid = threadIdx.x;
    pack_weight(Wkj,   HD, 4, fW1, tid, 512);
    pack_weight(Wrbf2, HD, 4, fW2, tid, 512);
    pack_weight(Wdown, HD, 4, fW3, tid, 512);
    __syncthreads();
    int lane = tid & 63, wave = tid >> 6;
    int m = lane & 15, q = lane >> 4;
    short* rt = rt0 + wave * (16 * RT_S);

    for (int tile = blockIdx.x * 8 + wave; tile < ntiles; tile += gridDim.x * 8) {
        long rowbase = (long)tile * 16;
        const float* xr = x   + (rowbase + m) * HD;
        const float* rr = rbf + (rowbase + m) * HD;
        short8 ax[4], ar[4];
#pragma unroll
        for (int kc = 0; kc < 4; kc++) {
            ax[kc] = ld8f(xr + kc * 32 + q * 8);
            ar[kc] = ld8f(rr + kc * 32 + q * 8);
        }
        f32x4 acc1[8], acc2[8];
#pragma unroll
        for (int ct = 0; ct < 8; ct++) { acc1[ct] = (f32x4){0,0,0,0}; acc2[ct] = (f32x4){0,0,0,0}; }
#pragma unroll
        for (int kc = 0; kc < 4; kc++) {
#pragma unroll
            for (int ct = 0; ct < 8; ct++) {
                acc1[ct] = mfma16(ax[kc], ld8(&fW1[((ct*4+kc)*64 + lane)*8]), acc1[ct]);
                acc2[ct] = mfma16(ar[kc], ld8(&fW2[((ct*4+kc)*64 + lane)*8]), acc2[ct]);
            }
        }
        // h = silu(.)*silu(.)  -> LDS (C-layout write)
#pragma unroll
        for (int ct = 0; ct < 8; ct++) {
            int col = ct * 16 + m;
            float bk = bkj[col];
            float br = brbf2[col];
#pragma unroll
            for (int r = 0; r < 4; r++) {
                float h = silu_f(acc1[ct][r] + bk) * silu_f(acc2[ct][r] + br);
                rt[(q*4 + r) * RT_S + col] = f2b(h);
            }
        }
        // A-frags of h
        short8 ah[4];
#pragma unroll
        for (int kc = 0; kc < 4; kc++) ah[kc] = ld8(&rt[m * RT_S + kc * 32 + q * 8]);
        f32x4 acc3[8];
#pragma unroll
        for (int ct = 0; ct < 8; ct++) acc3[ct] = (f32x4){0,0,0,0};
        gemm8<4>(ah, fW3, lane, acc3);
        // e = silu(. + bdown) -> LDS, then coalesced 16B global stores (bf16)
#pragma unroll
        for (int ct = 0; ct < 8; ct++) {
            int col = ct * 16 + m;
            float bd = bdown[col];
#pragma unroll
            for (int r = 0; r < 4; r++)
                rt[(q*4 + r) * RT_S + col] = f2b(silu_f(acc3[ct][r] + bd));
        }
        short* eg = e_down + (rowbase + m) * HD;
#pragma unroll
        for (int kc = 0; kc < 4; kc++)
            *(short8*)(eg + kc * 32 + q * 8) = ld8(&rt[m * RT_S + kc * 32 + q * 8]);
    }
}

// ---------------- Stage B ----------------
extern "C" __global__ __launch_bounds__(512)
void kB(const float* __restrict__ sbf, const int* __restrict__ idx_kj,
        const int* __restrict__ idx_ji,
        const float* __restrict__ W1, const float* __restrict__ W2,
        const float* __restrict__ Wup, const float* __restrict__ bup,
        const short* __restrict__ e_down, float* __restrict__ mb, int ntiles) {
    extern __shared__ short smem[];
    short* f1  = smem;               // 8*2*64*8 = 8192
    short* f2  = f1 + 8192;          // 16384
    short* f3  = f2 + 16384;         // 16384
    short* st0 = f3 + 16384;         // 8 * 16*72 = 9216
    short* rt0 = st0 + 9216;         // 8 * 16*RT_S
    int tid = threadIdx.x;
    pack_weight(W1, 42, 2, f1, tid, 512);
    pack_weight(W2, HD, 4, f2, tid, 512);
    pack_weight(Wup, HD, 4, f3, tid, 512);
    __syncthreads();
    int lane = tid & 63, wave = tid >> 6;
    int m = lane & 15, q = lane >> 4;
    short* st = st0 + wave * (16 * 72);
    short* rt = rt0 + wave * (16 * RT_S);
    int* sti = (int*)st;

    for (int tile = blockIdx.x * 8 + wave; tile < ntiles; tile += gridDim.x * 8) {
        long rowbase = (long)tile * 16;
        // zero [16][72] bf16 tile, then fill cols 0..41 from f32 sbf (42/row)
#pragma unroll
        for (int i = 0; i < 9; i++) sti[lane + i * 64] = 0;
        for (int i = lane; i < 672; i += 64) {
            int r = i / 42, d = i - r * 42;
            st[r * 72 + d] = f2b(sbf[(rowbase + r) * 42 + d]);
        }
        // GEMM1: [16,64pad] x W1
        short8 a0[2];
        a0[0] = ld8(&st[m * 72 + q * 8]);
        a0[1] = ld8(&st[m * 72 + 32 + q * 8]);
        f32x4 acc[8];
#pragma unroll
        for (int ct = 0; ct < 8; ct++) acc[ct] = (f32x4){0,0,0,0};
        gemm8<2>(a0, f1, lane, acc);
#pragma unroll
        for (int ct = 0; ct < 8; ct++) {
            int col = ct * 16 + m;
#pragma unroll
            for (int r = 0; r < 4; r++)
                rt[(q*4 + r) * RT_S + col] = f2b(silu_f(acc[ct][r]));
        }
        // GEMM2
        short8 a1[4];
#pragma unroll
        for (int kc = 0; kc < 4; kc++) a1[kc] = ld8(&rt[m * RT_S + kc * 32 + q * 8]);
#pragma unroll
        for (int ct = 0; ct < 8; ct++) acc[ct] = (f32x4){0,0,0,0};
        gemm8<4>(a1, f2, lane, acc);
#pragma unroll
        for (int ct = 0; ct < 8; ct++) {
            int col = ct * 16 + m;
#pragma unroll
            for (int r = 0; r < 4; r++)
                rt[(q*4 + r) * RT_S + col] = f2b(silu_f(acc[ct][r]));
        }
        // gather e_down[idx_kj] (A-layout), multiply by s, GEMM3 with Wup
        int ikj = idx_kj[rowbase + m];
        const short* ep = e_down + (long)ikj * HD;
        short8 p[4];
#pragma unroll
        for (int kc = 0; kc < 4; kc++) {
            short8 ek = ld8(ep + kc * 32 + q * 8);
            short8 ss = ld8(&rt[m * RT_S + kc * 32 + q * 8]);
            short8 pr;
#pragma unroll
            for (int j = 0; j < 8; j++) pr[j] = f2b(b2f(ss[j]) * b2f(ek[j]));
            p[kc] = pr;
        }
        f32x4 acc3[8];
#pragma unroll
        for (int ct = 0; ct < 8; ct++) acc3[ct] = (f32x4){0,0,0,0};
        gemm8<4>(p, f3, lane, acc3);
        // t = silu(. + bup); f32 scatter-add by idx_ji
        int jr[4];
#pragma unroll
        for (int r = 0; r < 4; r++) jr[r] = idx_ji[rowbase + q * 4 + r];
#pragma unroll
        for (int ct = 0; ct < 8; ct++) {
            int col = ct * 16 + m;
            float bu = bup[col];
#pragma unroll
            for (int r = 0; r < 4; r++) {
                float t = silu_f(acc3[ct][r] + bu);
                unsafeAtomicAdd(&mb[(long)jr[r] * HD + col], t);
            }
        }
    }
}

// ---------------- Stage C ----------------
extern "C" __global__ __launch_bounds__(512)
void kC(const float* __restrict__ mb, const float* __restrict__ x,
        const float* __restrict__ Wa, const float* __restrict__ ba,
        const float* __restrict__ Wb, const float* __restrict__ bb2,
        float* __restrict__ out, int ntiles) {
    extern __shared__ short smem[];
    short* f1  = smem;
    short* f2  = f1 + 16384;
    short* rt0 = f2 + 16384;
    int tid = threadIdx.x;
    pack_weight(Wa, HD, 4, f1, tid, 512);
    pack_weight(Wb, HD, 4, f2, tid, 512);
    __syncthreads();
    int lane = tid & 63, wave = tid >> 6;
    int m = lane & 15, q = lane >> 4;
    short* rt = rt0 + wave * (16 * RT_S);

    for (int tile = blockIdx.x * 8 + wave; tile < ntiles; tile += gridDim.x * 8) {
        long rowbase = (long)tile * 16;
        const float* mr = mb + (rowbase + m) * HD;
        short8 am[4];
#pragma unroll
        for (int kc = 0; kc < 4; kc++) am[kc] = ld8f(mr + kc * 32 + q * 8);
        f32x4 acc[8];
#pragma unroll
        for (int ct = 0; ct < 8; ct++) acc[ct] = (f32x4){0,0,0,0};
        gemm8<4>(am, f1, lane, acc);
#pragma unroll
        for (int ct = 0; ct < 8; ct++) {
            int col = ct * 16 + m;
            float bav = ba[col];
#pragma unroll
            for (int r = 0; r < 4; r++)
                rt[(q*4 + r) * RT_S + col] = f2b(silu_f(acc[ct][r] + bav));
        }
        short8 ah[4];
#pragma unroll
        for (int kc = 0; kc < 4; kc++) ah[kc] = ld8(&rt[m * RT_S + kc * 32 + q * 8]);
#pragma unroll
        for (int ct = 0; ct < 8; ct++) acc[ct] = (f32x4){0,0,0,0};
        gemm8<4>(ah, f2, lane, acc);
        // out = mb + silu(. + bb) + x   (f32, direct C-layout stores)
#pragma unroll
        for (int ct = 0; ct < 8; ct++) {
            int col = ct * 16 + m;
            float bbv = bb2[col];
#pragma unroll
            for (int r = 0; r < 4; r++) {
                long grow = rowbase + q * 4 + r;
                out[grow * HD + col] = mb[grow * HD + col]
                                     + silu_f(acc[ct][r] + bbv)
                                     + x[grow * HD + col];
            }
        }
    }
}

extern "C" void kernel_launch(void* const* d_in, const int* in_sizes, int n_in,
                              void* d_out, int out_size, void* d_ws, size_t ws_size,
                              hipStream_t stream) {
    const float* x      = (const float*)d_in[0];
    const float* rbf    = (const float*)d_in[1];
    const float* sbf    = (const float*)d_in[2];
    const int*   idx_kj = (const int*)d_in[3];
    const int*   idx_ji = (const int*)d_in[4];
    const float* W_rbf2 = (const float*)d_in[5];
    const float* b_rbf2 = (const float*)d_in[6];
    const float* W_sbf1 = (const float*)d_in[7];
    const float* W_sbf2 = (const float*)d_in[8];
    const float* W_kj   = (const float*)d_in[9];
    const float* b_kj   = (const float*)d_in[10];
    const float* W_down = (const float*)d_in[11];
    const float* b_down = (const float*)d_in[12];
    const float* W_up   = (const float*)d_in[13];
    const float* b_up   = (const float*)d_in[14];
    const float* W_r1a  = (const float*)d_in[15];
    const float* b_r1a  = (const float*)d_in[16];
    const float* W_r1b  = (const float*)d_in[17];
    const float* b_r1b  = (const float*)d_in[18];

    int E = in_sizes[0] / HD;
    int T = in_sizes[3];

    short* e_down = (short*)d_ws;                              // E*128 bf16 = 64 MB
    float* mb = (float*)((char*)d_ws + (size_t)E * HD * 2);    // E*128 f32  = 128 MB
    hipMemsetAsync(mb, 0, (size_t)E * HD * 4, stream);

    int ntA = E / 16;
    int ntB = T / 16;
    size_t ldsA = (size_t)(3 * 16384 + 8 * 16 * RT_S) * 2;
    size_t ldsB = (size_t)(8192 + 16384 + 16384 + 8 * 16 * 72 + 8 * 16 * RT_S) * 2;
    size_t ldsC = (size_t)(2 * 16384 + 8 * 16 * RT_S) * 2;

    kA<<<256, 512, ldsA, stream>>>(x, rbf, W_kj, b_kj, W_rbf2, b_rbf2,
                                   W_down, b_down, e_down, ntA);
    kB<<<256, 512, ldsB, stream>>>(sbf, idx_kj, idx_ji, W_sbf1, W_sbf2,
                                   W_up, b_up, e_down, mb, ntB);
    kC<<<256, 512, ldsC, stream>>>(mb, x, W_r1a, b_r1a, W_r1b, b_r1b,
                                   (float*)d_out, ntA);
}

// Round 3
// 1022.187 us; speedup vs baseline: 1.0983x; 1.0983x over previous
//
#include <hip/hip_runtime.h>
#include <hip/hip_bf16.h>

// DimeNet InteractionBlock, MI355X/gfx950.
// Float tensors are FLOAT32 at the memory interface; internal GEMMs bf16 MFMA.
// Stage A (kA): e_down = silu( (silu(x Wkj+b) * silu(rbf Wrbf2+b)) Wdown + b )  [E,128] bf16 -> ws
// Stage B (kB): t = silu( (e_down[idx_kj] * silu(silu(sbf W1) W2)) Wup + b );
//               f32 atomicAdd into mb[idx_ji]                                   [E,128] f32 -> ws
// Stage C (kC): out = mb + silu(silu(mb Wr1a+b) Wr1b+b) + x                     [E,128] f32
//
// R3 change: occupancy. kB 512->1024 thr (8->16 waves/CU, st aliased into rt),
// kA 512->896 (14 waves), kC 512->1024 (16 waves). LDS/block: kA 155.5KB,
// kB 148KB, kC 132KB -- all fit 160KB with 1 block/CU but 2x the waves.

#define HD 128

typedef short  short8 __attribute__((ext_vector_type(8)));
typedef __bf16 bf16x8 __attribute__((ext_vector_type(8)));
typedef float  f32x4  __attribute__((ext_vector_type(4)));

__device__ __forceinline__ float b2f(short s) {
    unsigned u = ((unsigned)(unsigned short)s) << 16;
    return __builtin_bit_cast(float, u);
}
__device__ __forceinline__ short f2b(float f) {
    return __builtin_bit_cast(short, __float2bfloat16(f));
}
__device__ __forceinline__ float silu_f(float v) {
    return v * __builtin_amdgcn_rcpf(1.0f + __expf(-v));
}
__device__ __forceinline__ short8 ld8(const short* p) { return *(const short8*)p; }

__device__ __forceinline__ f32x4 mfma16(short8 a, short8 b, f32x4 c) {
    return __builtin_amdgcn_mfma_f32_16x16x32_bf16(
        __builtin_bit_cast(bf16x8, a), __builtin_bit_cast(bf16x8, b), c, 0, 0, 0);
}

// Convert 8 consecutive f32 at p to a bf16 short8 fragment chunk.
__device__ __forceinline__ short8 ld8f(const float* p) {
    f32x4 v0 = *(const f32x4*)p;
    f32x4 v1 = *(const f32x4*)(p + 4);
    short8 r;
#pragma unroll
    for (int j = 0; j < 4; j++) { r[j] = f2b(v0[j]); r[4 + j] = f2b(v1[j]); }
    return r;
}

// Pack f32 weight W[K x 128] (row-major) into LDS bf16 fragment order:
// frag[((ct*KC+kc)*64 + lane)*8 + j] = B[k=kc*32+(lane>>4)*8+j][n=ct*16+(lane&15)]
__device__ void pack_weight(const float* __restrict__ W, int Kact, int KC,
                            short* frag, int tid, int nth) {
    int total = 8 * KC * 64;
    for (int e = tid; e < total; e += nth) {
        int lane = e & 63;
        int slot = e >> 6;          // ct*KC + kc
        int ct = slot / KC;
        int kc = slot - ct * KC;
        int n  = ct * 16 + (lane & 15);
        int kb = kc * 32 + (lane >> 4) * 8;
        short8 v;
#pragma unroll
        for (int j = 0; j < 8; j++) {
            int k = kb + j;
            v[j] = (k < Kact) ? f2b(W[k * HD + n]) : (short)0;
        }
        *(short8*)&frag[(slot * 64 + lane) * 8] = v;
    }
}

template <int KC>
__device__ __forceinline__ void gemm8(const short8* a, const short* fragW,
                                      int lane, f32x4* acc) {
#pragma unroll
    for (int kc = 0; kc < KC; kc++) {
#pragma unroll
        for (int ct = 0; ct < 8; ct++) {
            short8 b = ld8(&fragW[((ct * KC + kc) * 64 + lane) * 8]);
            acc[ct] = mfma16(a[kc], b, acc[ct]);
        }
    }
}

#define RT_S 136  // round-trip tile stride (bf16 elems); 272B rows, 16B-aligned

// ---------------- Stage A (14 waves) ----------------
extern "C" __global__ __launch_bounds__(896)
void kA(const float* __restrict__ x, const float* __restrict__ rbf,
        const float* __restrict__ Wkj, const float* __restrict__ bkj,
        const float* __restrict__ Wrbf2, const float* __restrict__ brbf2,
        const float* __restrict__ Wdown, const float* __restrict__ bdown,
        short* __restrict__ e_down, int ntiles) {
    extern __shared__ short smem[];
    short* fW1 = smem;               // 16384 shorts each
    short* fW2 = fW1 + 16384;
    short* fW3 = fW2 + 16384;
    short* rt0 = fW3 + 16384;        // 14 waves * 16*RT_S
    int tid = threadIdx.x;
    pack_weight(Wkj,   HD, 4, fW1, tid, 896);
    pack_weight(Wrbf2, HD, 4, fW2, tid, 896);
    pack_weight(Wdown, HD, 4, fW3, tid, 896);
    __syncthreads();
    int lane = tid & 63, wave = tid >> 6;
    int m = lane & 15, q = lane >> 4;
    short* rt = rt0 + wave * (16 * RT_S);

    for (int tile = blockIdx.x * 14 + wave; tile < ntiles; tile += gridDim.x * 14) {
        long rowbase = (long)tile * 16;
        const float* xr = x   + (rowbase + m) * HD;
        const float* rr = rbf + (rowbase + m) * HD;
        short8 ax[4], ar[4];
#pragma unroll
        for (int kc = 0; kc < 4; kc++) {
            ax[kc] = ld8f(xr + kc * 32 + q * 8);
            ar[kc] = ld8f(rr + kc * 32 + q * 8);
        }
        f32x4 acc1[8], acc2[8];
#pragma unroll
        for (int ct = 0; ct < 8; ct++) { acc1[ct] = (f32x4){0,0,0,0}; acc2[ct] = (f32x4){0,0,0,0}; }
#pragma unroll
        for (int kc = 0; kc < 4; kc++) {
#pragma unroll
            for (int ct = 0; ct < 8; ct++) {
                acc1[ct] = mfma16(ax[kc], ld8(&fW1[((ct*4+kc)*64 + lane)*8]), acc1[ct]);
                acc2[ct] = mfma16(ar[kc], ld8(&fW2[((ct*4+kc)*64 + lane)*8]), acc2[ct]);
            }
        }
        // h = silu(.)*silu(.)  -> LDS (C-layout write)
#pragma unroll
        for (int ct = 0; ct < 8; ct++) {
            int col = ct * 16 + m;
            float bk = bkj[col];
            float br = brbf2[col];
#pragma unroll
            for (int r = 0; r < 4; r++) {
                float h = silu_f(acc1[ct][r] + bk) * silu_f(acc2[ct][r] + br);
                rt[(q*4 + r) * RT_S + col] = f2b(h);
            }
        }
        short8 ah[4];
#pragma unroll
        for (int kc = 0; kc < 4; kc++) ah[kc] = ld8(&rt[m * RT_S + kc * 32 + q * 8]);
        f32x4 acc3[8];
#pragma unroll
        for (int ct = 0; ct < 8; ct++) acc3[ct] = (f32x4){0,0,0,0};
        gemm8<4>(ah, fW3, lane, acc3);
#pragma unroll
        for (int ct = 0; ct < 8; ct++) {
            int col = ct * 16 + m;
            float bd = bdown[col];
#pragma unroll
            for (int r = 0; r < 4; r++)
                rt[(q*4 + r) * RT_S + col] = f2b(silu_f(acc3[ct][r] + bd));
        }
        short* eg = e_down + (rowbase + m) * HD;
#pragma unroll
        for (int kc = 0; kc < 4; kc++)
            *(short8*)(eg + kc * 32 + q * 8) = ld8(&rt[m * RT_S + kc * 32 + q * 8]);
    }
}

// ---------------- Stage B (16 waves, st aliased into rt) ----------------
extern "C" __global__ __launch_bounds__(1024)
void kB(const float* __restrict__ sbf, const int* __restrict__ idx_kj,
        const int* __restrict__ idx_ji,
        const float* __restrict__ W1, const float* __restrict__ W2,
        const float* __restrict__ Wup, const float* __restrict__ bup,
        const short* __restrict__ e_down, float* __restrict__ mb, int ntiles) {
    extern __shared__ short smem[];
    short* f1  = smem;               // 8192 shorts
    short* f2  = f1 + 8192;          // 16384
    short* f3  = f2 + 16384;         // 16384
    short* rt0 = f3 + 16384;         // 16 waves * 16*RT_S (st aliases rt)
    int tid = threadIdx.x;
    pack_weight(W1, 42, 2, f1, tid, 1024);
    pack_weight(W2, HD, 4, f2, tid, 1024);
    pack_weight(Wup, HD, 4, f3, tid, 1024);
    __syncthreads();
    int lane = tid & 63, wave = tid >> 6;
    int m = lane & 15, q = lane >> 4;
    short* rt = rt0 + wave * (16 * RT_S);
    short* st = rt;                  // alias: st [16][72] lives in rt's space
    int* sti = (int*)st;
    const float2* sg2 = (const float2*)sbf;   // 21 float2 per 42-f32 row

    for (int tile = blockIdx.x * 16 + wave; tile < ntiles; tile += gridDim.x * 16) {
        long rowbase = (long)tile * 16;
        // zero [16][72] bf16 tile (2304B), fill cols 0..41 via float2 loads
#pragma unroll
        for (int i = 0; i < 9; i++) sti[lane + i * 64] = 0;
#pragma unroll
        for (int i = lane; i < 336; i += 64) {
            int r = i / 21, d = i - r * 21;
            float2 v = sg2[(rowbase + r) * 21 + d];
            st[r * 72 + d * 2]     = f2b(v.x);
            st[r * 72 + d * 2 + 1] = f2b(v.y);
        }
        // GEMM1: [16,64pad] x W1
        short8 a0[2];
        a0[0] = ld8(&st[m * 72 + q * 8]);
        a0[1] = ld8(&st[m * 72 + 32 + q * 8]);
        f32x4 acc[8];
#pragma unroll
        for (int ct = 0; ct < 8; ct++) acc[ct] = (f32x4){0,0,0,0};
        gemm8<2>(a0, f1, lane, acc);
#pragma unroll
        for (int ct = 0; ct < 8; ct++) {
            int col = ct * 16 + m;
#pragma unroll
            for (int r = 0; r < 4; r++)
                rt[(q*4 + r) * RT_S + col] = f2b(silu_f(acc[ct][r]));
        }
        // GEMM2
        short8 a1[4];
#pragma unroll
        for (int kc = 0; kc < 4; kc++) a1[kc] = ld8(&rt[m * RT_S + kc * 32 + q * 8]);
#pragma unroll
        for (int ct = 0; ct < 8; ct++) acc[ct] = (f32x4){0,0,0,0};
        gemm8<4>(a1, f2, lane, acc);
#pragma unroll
        for (int ct = 0; ct < 8; ct++) {
            int col = ct * 16 + m;
#pragma unroll
            for (int r = 0; r < 4; r++)
                rt[(q*4 + r) * RT_S + col] = f2b(silu_f(acc[ct][r]));
        }
        // gather e_down[idx_kj] (A-layout), multiply by s, GEMM3 with Wup
        int ikj = idx_kj[rowbase + m];
        const short* ep = e_down + (long)ikj * HD;
        short8 p[4];
#pragma unroll
        for (int kc = 0; kc < 4; kc++) {
            short8 ek = ld8(ep + kc * 32 + q * 8);
            short8 ss = ld8(&rt[m * RT_S + kc * 32 + q * 8]);
            short8 pr;
#pragma unroll
            for (int j = 0; j < 8; j++) pr[j] = f2b(b2f(ss[j]) * b2f(ek[j]));
            p[kc] = pr;
        }
        f32x4 acc3[8];
#pragma unroll
        for (int ct = 0; ct < 8; ct++) acc3[ct] = (f32x4){0,0,0,0};
        gemm8<4>(p, f3, lane, acc3);
        // t = silu(. + bup); f32 scatter-add by idx_ji
        int jr[4];
#pragma unroll
        for (int r = 0; r < 4; r++) jr[r] = idx_ji[rowbase + q * 4 + r];
#pragma unroll
        for (int ct = 0; ct < 8; ct++) {
            int col = ct * 16 + m;
            float bu = bup[col];
#pragma unroll
            for (int r = 0; r < 4; r++) {
                float t = silu_f(acc3[ct][r] + bu);
                unsafeAtomicAdd(&mb[(long)jr[r] * HD + col], t);
            }
        }
    }
}

// ---------------- Stage C (16 waves) ----------------
extern "C" __global__ __launch_bounds__(1024)
void kC(const float* __restrict__ mb, const float* __restrict__ x,
        const float* __restrict__ Wa, const float* __restrict__ ba,
        const float* __restrict__ Wb, const float* __restrict__ bb2,
        float* __restrict__ out, int ntiles) {
    extern __shared__ short smem[];
    short* f1  = smem;
    short* f2  = f1 + 16384;
    short* rt0 = f2 + 16384;
    int tid = threadIdx.x;
    pack_weight(Wa, HD, 4, f1, tid, 1024);
    pack_weight(Wb, HD, 4, f2, tid, 1024);
    __syncthreads();
    int lane = tid & 63, wave = tid >> 6;
    int m = lane & 15, q = lane >> 4;
    short* rt = rt0 + wave * (16 * RT_S);

    for (int tile = blockIdx.x * 16 + wave; tile < ntiles; tile += gridDim.x * 16) {
        long rowbase = (long)tile * 16;
        const float* mr = mb + (rowbase + m) * HD;
        short8 am[4];
#pragma unroll
        for (int kc = 0; kc < 4; kc++) am[kc] = ld8f(mr + kc * 32 + q * 8);
        f32x4 acc[8];
#pragma unroll
        for (int ct = 0; ct < 8; ct++) acc[ct] = (f32x4){0,0,0,0};
        gemm8<4>(am, f1, lane, acc);
#pragma unroll
        for (int ct = 0; ct < 8; ct++) {
            int col = ct * 16 + m;
            float bav = ba[col];
#pragma unroll
            for (int r = 0; r < 4; r++)
                rt[(q*4 + r) * RT_S + col] = f2b(silu_f(acc[ct][r] + bav));
        }
        short8 ah[4];
#pragma unroll
        for (int kc = 0; kc < 4; kc++) ah[kc] = ld8(&rt[m * RT_S + kc * 32 + q * 8]);
#pragma unroll
        for (int ct = 0; ct < 8; ct++) acc[ct] = (f32x4){0,0,0,0};
        gemm8<4>(ah, f2, lane, acc);
        // out = mb + silu(. + bb) + x  (per-(ct,r) stores cover full 64B lines)
#pragma unroll
        for (int ct = 0; ct < 8; ct++) {
            int col = ct * 16 + m;
            float bbv = bb2[col];
#pragma unroll
            for (int r = 0; r < 4; r++) {
                long grow = rowbase + q * 4 + r;
                out[grow * HD + col] = mb[grow * HD + col]
                                     + silu_f(acc[ct][r] + bbv)
                                     + x[grow * HD + col];
            }
        }
    }
}

extern "C" void kernel_launch(void* const* d_in, const int* in_sizes, int n_in,
                              void* d_out, int out_size, void* d_ws, size_t ws_size,
                              hipStream_t stream) {
    const float* x      = (const float*)d_in[0];
    const float* rbf    = (const float*)d_in[1];
    const float* sbf    = (const float*)d_in[2];
    const int*   idx_kj = (const int*)d_in[3];
    const int*   idx_ji = (const int*)d_in[4];
    const float* W_rbf2 = (const float*)d_in[5];
    const float* b_rbf2 = (const float*)d_in[6];
    const float* W_sbf1 = (const float*)d_in[7];
    const float* W_sbf2 = (const float*)d_in[8];
    const float* W_kj   = (const float*)d_in[9];
    const float* b_kj   = (const float*)d_in[10];
    const float* W_down = (const float*)d_in[11];
    const float* b_down = (const float*)d_in[12];
    const float* W_up   = (const float*)d_in[13];
    const float* b_up   = (const float*)d_in[14];
    const float* W_r1a  = (const float*)d_in[15];
    const float* b_r1a  = (const float*)d_in[16];
    const float* W_r1b  = (const float*)d_in[17];
    const float* b_r1b  = (const float*)d_in[18];

    int E = in_sizes[0] / HD;
    int T = in_sizes[3];

    short* e_down = (short*)d_ws;                              // E*128 bf16 = 64 MB
    float* mb = (float*)((char*)d_ws + (size_t)E * HD * 2);    // E*128 f32  = 128 MB
    hipMemsetAsync(mb, 0, (size_t)E * HD * 4, stream);

    int ntA = E / 16;
    int ntB = T / 16;
    size_t ldsA = (size_t)(3 * 16384 + 14 * 16 * RT_S) * 2;    // 159232 B
    size_t ldsB = (size_t)(8192 + 16384 + 16384 + 16 * 16 * RT_S) * 2;  // 151552 B
    size_t ldsC = (size_t)(2 * 16384 + 16 * 16 * RT_S) * 2;    // 135168 B

    kA<<<256, 896, ldsA, stream>>>(x, rbf, W_kj, b_kj, W_rbf2, b_rbf2,
                                   W_down, b_down, e_down, ntA);
    kB<<<256, 1024, ldsB, stream>>>(sbf, idx_kj, idx_ji, W_sbf1, W_sbf2,
                                    W_up, b_up, e_down, mb, ntB);
    kC<<<256, 1024, ldsC, stream>>>(mb, x, W_r1a, b_r1a, W_r1b, b_r1b,
                                    (float*)d_out, ntA);
}